// Round 6
// baseline (455.651 us; speedup 1.0000x reference)
//
#include <hip/hip_runtime.h>
#include <hip/hip_bf16.h>
#include <cstdint>

#define LRELU_SLOPE 0.2f

typedef short bf16x8 __attribute__((ext_vector_type(8)));
typedef float f32x4  __attribute__((ext_vector_type(4)));

__device__ __forceinline__ float b2f(unsigned short u) {
  return __uint_as_float(((unsigned int)u) << 16);
}
__device__ __forceinline__ unsigned short f2b(float f) {  // RNE
  unsigned int u = __float_as_uint(f);
  return (unsigned short)((u + 0x7fff + ((u >> 16) & 1)) >> 16);
}

__device__ __forceinline__ void gload16(const void* g, void* l) {
  __builtin_amdgcn_global_load_lds(
      (const __attribute__((address_space(1))) unsigned int*)g,
      (__attribute__((address_space(3))) unsigned int*)l, 16, 0, 0);
}

// ---------------------------------------------- fused x->bf16 pad + csr_count
__global__ __launch_bounds__(256)
void prep_x_count(const float* __restrict__ x, unsigned short* __restrict__ o,
                  int M, int Mpad, const int* __restrict__ ei, int E, int Etot,
                  int* __restrict__ count) {
  const int i = blockIdx.x * 256 + threadIdx.x;
  // part A: convert x[M,256] -> bf16 padded to Mpad rows
  if (i < Mpad * 64) {
    const int row = i >> 6;
    const int c4  = (i & 63) * 4;
    ushort4 v = make_ushort4(0, 0, 0, 0);
    if (row < M) {
      const float4 f = *(const float4*)&x[(size_t)row * 256 + c4];
      v = make_ushort4(f2b(f.x), f2b(f.y), f2b(f.z), f2b(f.w));
    }
    *(ushort4*)&o[(size_t)row * 256 + c4] = v;
  }
  // part B: degree count
  if (i < Etot) {
    const int d = (i < E) ? ei[E + i] : (i - E);
    atomicAdd(&count[d], 1);
  }
}

// ------------------------------------- both weight transposes in one launch
__global__ __launch_bounds__(256)
void cvt_wts(const float* __restrict__ W1, const float* __restrict__ W2,
             unsigned short* __restrict__ W1T, unsigned short* __restrict__ W2T) {
  int j = blockIdx.x * 256 + threadIdx.x;
  if (j < 512 * 256) {        // W1T[n*256+k] = W1[k*512+n]
    const int n = j >> 8, k = j & 255;
    W1T[j] = f2b(W1[(size_t)k * 512 + n]);
  } else {                    // W2T[n*512+k] = W2[k*256+n]
    j -= 512 * 256;
    const int n = j >> 9, k = j & 511;
    W2T[j] = f2b(W2[(size_t)k * 256 + n]);
  }
}

// ------------------------------------------------------------- CSR scan
__global__ __launch_bounds__(256)
void scan_blocksum(const int* __restrict__ count, int* __restrict__ bsum, int Nn) {
  const int i0 = blockIdx.x * 1024 + threadIdx.x * 4;
  int s = 0;
#pragma unroll
  for (int k = 0; k < 4; ++k) { const int i = i0 + k; if (i < Nn) s += count[i]; }
#pragma unroll
  for (int off = 1; off < 64; off <<= 1) s += __shfl_xor(s, off);
  __shared__ int ws[4];
  if ((threadIdx.x & 63) == 0) ws[threadIdx.x >> 6] = s;
  __syncthreads();
  if (threadIdx.x == 0) bsum[blockIdx.x] = ws[0] + ws[1] + ws[2] + ws[3];
}

__global__ __launch_bounds__(64)
void scan_top(const int* __restrict__ bsum, int* __restrict__ boff,
              int* __restrict__ rowptrN, int nb) {
  const int t = threadIdx.x;
  const int v = (t < nb) ? bsum[t] : 0;
  int incl = v;
#pragma unroll
  for (int off = 1; off < 64; off <<= 1) {
    const int u = __shfl_up(incl, off);
    if (t >= off) incl += u;
  }
  if (t < nb) boff[t] = incl - v;
  if (t == 63) *rowptrN = incl;
}

__global__ __launch_bounds__(256)
void scan_apply(const int* __restrict__ count, const int* __restrict__ boff,
                int* __restrict__ rowptr, int* __restrict__ cursor, int Nn) {
  const int t = threadIdx.x;
  const int lane = t & 63;
  const int w = t >> 6;
  const int i0 = blockIdx.x * 1024 + t * 4;
  int c[4]; int s = 0;
#pragma unroll
  for (int k = 0; k < 4; ++k) { const int i = i0 + k; c[k] = (i < Nn) ? count[i] : 0; s += c[k]; }
  int incl = s;
#pragma unroll
  for (int off = 1; off < 64; off <<= 1) {
    const int u = __shfl_up(incl, off);
    if (lane >= off) incl += u;
  }
  __shared__ int ws[4];
  if (lane == 63) ws[w] = incl;
  __syncthreads();
  int woff = 0;
  for (int k = 0; k < w; ++k) woff += ws[k];
  int base = boff[blockIdx.x] + woff + incl - s;
#pragma unroll
  for (int k = 0; k < 4; ++k) {
    const int i = i0 + k;
    if (i < Nn) { rowptr[i] = base; cursor[i] = base; base += c[k]; }
  }
}

__global__ __launch_bounds__(256)
void csr_scatter(const int* __restrict__ ei, int E, int Etot,
                 int* __restrict__ cursor, int* __restrict__ srcs,
                 int* __restrict__ dsts) {
  const int i = blockIdx.x * 256 + threadIdx.x;
  if (i >= Etot) return;
  const int s = (i < E) ? ei[i]     : (i - E);
  const int d = (i < E) ? ei[E + i] : (i - E);
  const int pos = atomicAdd(&cursor[d], 1);
  srcs[pos] = s;
  dsts[pos] = d;
}

// ------------------------------- bf16 MFMA GEMM + fused attention-logit dots
// C[M,N](bf16) = A[Mpad,K] @ BT[N,K]^T; also es[row,head] += h.a_src partials.
template<int KSTEPS>
__global__ __launch_bounds__(256)
void gemm_bf16(const unsigned short* __restrict__ A,
               const unsigned short* __restrict__ BT,
               unsigned short* __restrict__ C, int M, int Nn, int K,
               const float* __restrict__ asrc, const float* __restrict__ adst,
               float* __restrict__ es, float* __restrict__ ed,
               int H, int lgC) {
  __shared__ unsigned short As[2][128 * 32];
  __shared__ unsigned short Bs[2][128 * 32];
  const int tid  = threadIdx.x;
  const int lane = tid & 63;
  const int wave = tid >> 6;
  const int wm = wave >> 1, wn = wave & 1;
  const int brow = blockIdx.y * 128;
  const int bcol = blockIdx.x * 128;
  const int srow  = tid >> 2;
  const int sslot = tid & 3;
  const int sswz  = sslot ^ (srow & 3);
  const size_t aBase0 = (size_t)(brow + srow) * K + sswz * 8;
  const size_t aBase1 = (size_t)(brow + 64 + srow) * K + sswz * 8;
  const size_t bBase0 = (size_t)(bcol + srow) * K + sswz * 8;
  const size_t bBase1 = (size_t)(bcol + 64 + srow) * K + sswz * 8;
  const int ldsOff0 = srow * 32 + sslot * 8;
  const int ldsOff1 = (64 + srow) * 32 + sslot * 8;

  f32x4 acc[4][4] = {};
  const int u   = lane >> 4;
  const int r15 = lane & 15;
  const int sw  = u ^ (r15 & 3);

  auto stage = [&](int buf, int ks) {
    const int k0 = ks * 32;
    gload16(A + aBase0 + k0, &As[buf][ldsOff0]);
    gload16(A + aBase1 + k0, &As[buf][ldsOff1]);
    gload16(BT + bBase0 + k0, &Bs[buf][ldsOff0]);
    gload16(BT + bBase1 + k0, &Bs[buf][ldsOff1]);
  };

  stage(0, 0);
  asm volatile("s_waitcnt vmcnt(0)" ::: "memory");
  __syncthreads();
  int cur = 0;
#pragma unroll
  for (int ks = 0; ks < KSTEPS; ++ks) {
    if (ks + 1 < KSTEPS) stage(cur ^ 1, ks + 1);
    bf16x8 af[4], bfv[4];
#pragma unroll
    for (int m = 0; m < 4; ++m) {
      const int row = wm * 64 + m * 16 + r15;
      af[m]  = *(const bf16x8*)&As[cur][row * 32 + sw * 8];
      const int col = wn * 64 + m * 16 + r15;
      bfv[m] = *(const bf16x8*)&Bs[cur][col * 32 + sw * 8];
    }
#pragma unroll
    for (int m = 0; m < 4; ++m)
#pragma unroll
      for (int n = 0; n < 4; ++n)
        acc[m][n] = __builtin_amdgcn_mfma_f32_16x16x32_bf16(
            af[m], bfv[n], acc[m][n], 0, 0, 0);
    if (ks + 1 < KSTEPS) {
      asm volatile("s_waitcnt vmcnt(0)" ::: "memory");
      __syncthreads();
      cur ^= 1;
    }
  }
  // ---- C write (row = ... + u*4 + r, col = ... + r15) ----
#pragma unroll
  for (int m = 0; m < 4; ++m) {
    const int r0 = brow + wm * 64 + m * 16 + u * 4;
#pragma unroll
    for (int n = 0; n < 4; ++n) {
      const int cc = bcol + wn * 64 + n * 16 + r15;
#pragma unroll
      for (int r = 0; r < 4; ++r)
        if (r0 + r < M) C[(size_t)(r0 + r) * Nn + cc] = f2b(acc[m][n][r]);
    }
  }
  // ---- fused attention logits: es/ed[row,head] += sum_cols h*a ----
  const int head = bcol >> lgC;
  float asv[4], adv[4];
#pragma unroll
  for (int n = 0; n < 4; ++n) {
    const int cc = bcol + wn * 64 + n * 16 + r15;
    asv[n] = asrc[cc];
    adv[n] = adst[cc];
  }
#pragma unroll
  for (int m = 0; m < 4; ++m) {
#pragma unroll
    for (int r = 0; r < 4; ++r) {
      float pes = 0.f, ped = 0.f;
#pragma unroll
      for (int n = 0; n < 4; ++n) {
        pes = fmaf(acc[m][n][r], asv[n], pes);
        ped = fmaf(acc[m][n][r], adv[n], ped);
      }
#pragma unroll
      for (int off = 1; off < 16; off <<= 1) {
        pes += __shfl_xor(pes, off);
        ped += __shfl_xor(ped, off);
      }
      if (r15 == 0) {
        const int row = brow + wm * 64 + m * 16 + u * 4 + r;
        if (row < M) {
          unsafeAtomicAdd(&es[row * H + head], pes);
          unsafeAtomicAdd(&ed[row * H + head], ped);
        }
      }
    }
  }
}

// -------------------------- edge-parallel softmax numerator (CSR order) + sum
template<int H>
__global__ __launch_bounds__(256)
void ex_compute(const int* __restrict__ srcs, const int* __restrict__ dsts,
                const float* __restrict__ es, const float* __restrict__ ed,
                float* __restrict__ exCSR, float* __restrict__ s, int Etot) {
  const int p = blockIdx.x * 256 + threadIdx.x;
  if (p >= Etot) return;
  const int sN = srcs[p], dN = dsts[p];
  if constexpr (H == 4) {
    const float4 a = *(const float4*)&es[sN * 4];
    const float4 b = *(const float4*)&ed[dN * 4];
    float4 v;
    float e0 = a.x + b.x, e1 = a.y + b.y, e2 = a.z + b.z, e3 = a.w + b.w;
    e0 = (e0 > 0.f) ? e0 : LRELU_SLOPE * e0;
    e1 = (e1 > 0.f) ? e1 : LRELU_SLOPE * e1;
    e2 = (e2 > 0.f) ? e2 : LRELU_SLOPE * e2;
    e3 = (e3 > 0.f) ? e3 : LRELU_SLOPE * e3;
    v.x = __expf(e0); v.y = __expf(e1); v.z = __expf(e2); v.w = __expf(e3);
    *(float4*)&exCSR[p * 4] = v;
    unsafeAtomicAdd(&s[dN * 4 + 0], v.x);
    unsafeAtomicAdd(&s[dN * 4 + 1], v.y);
    unsafeAtomicAdd(&s[dN * 4 + 2], v.z);
    unsafeAtomicAdd(&s[dN * 4 + 3], v.w);
  } else {
    float e = es[sN] + ed[dN];
    e = (e > 0.f) ? e : LRELU_SLOPE * e;
    const float v = __expf(e);
    exCSR[p] = v;
    unsafeAtomicAdd(&s[dN], v);
  }
}

// ---------------------- gather GAT aggregation + fused bias/LayerNorm(/ReLU)
// one wave per node; alpha streamed from CSR-ordered exCSR; 4-deep pipeline.
template<int H, int C, bool RELU, bool BFOUT>
__global__ __launch_bounds__(256)
void gat_agg_ln(const int* __restrict__ rowptr, const int* __restrict__ srcs,
                const float* __restrict__ exCSR, const float* __restrict__ s,
                const unsigned short* __restrict__ h,
                const float* __restrict__ bias, const float* __restrict__ lng,
                const float* __restrict__ lnb, unsigned short* __restrict__ obf,
                float* __restrict__ of32, int Nn) {
  constexpr int HC = H * C;
  constexpr int F  = HC / 64;          // 8 (layer1) or 4 (layer2)
  const int wave = threadIdx.x >> 6;
  const int lane = threadIdx.x & 63;
  const int n = blockIdx.x * 4 + wave;
  if (n >= Nn) return;
  const int beg = rowptr[n];
  const int deg = rowptr[n + 1] - beg;
  const int hl = (lane * F) / C;
  const float inv_s = 1.0f / (s[n * H + hl] + 1e-16f);

  float acc[F];
#pragma unroll
  for (int i = 0; i < F; ++i) acc[i] = 0.f;

  auto fma_rows = [&](const ushort4* v0, const ushort4* v1, const float* a, int cnt) {
    for (int q = 0; q < cnt; ++q) {
      acc[0] = fmaf(b2f(v0[q].x), a[q], acc[0]);
      acc[1] = fmaf(b2f(v0[q].y), a[q], acc[1]);
      acc[2] = fmaf(b2f(v0[q].z), a[q], acc[2]);
      acc[3] = fmaf(b2f(v0[q].w), a[q], acc[3]);
      if constexpr (F == 8) {
        acc[4] = fmaf(b2f(v1[q].x), a[q], acc[4]);
        acc[5] = fmaf(b2f(v1[q].y), a[q], acc[5]);
        acc[6] = fmaf(b2f(v1[q].z), a[q], acc[6]);
        acc[7] = fmaf(b2f(v1[q].w), a[q], acc[7]);
      }
    }
  };

  int j = 0;
  for (; j + 4 <= deg; j += 4) {
    int s4[4];
    float a4[4];
#pragma unroll
    for (int q = 0; q < 4; ++q) s4[q] = srcs[beg + j + q];
#pragma unroll
    for (int q = 0; q < 4; ++q) a4[q] = exCSR[(beg + j + q) * H + hl] * inv_s;
    ushort4 v0[4], v1[4];
#pragma unroll
    for (int q = 0; q < 4; ++q) {
      const unsigned short* hp = &h[(size_t)s4[q] * HC + lane * F];
      v0[q] = *(const ushort4*)hp;
      if constexpr (F == 8) v1[q] = *(const ushort4*)(hp + 4);
    }
    fma_rows(v0, v1, a4, 4);
  }
  for (; j < deg; ++j) {
    const int src = srcs[beg + j];
    const float a = exCSR[(beg + j) * H + hl] * inv_s;
    const unsigned short* hp = &h[(size_t)src * HC + lane * F];
    ushort4 v0 = *(const ushort4*)hp, v1;
    if constexpr (F == 8) v1 = *(const ushort4*)(hp + 4);
    fma_rows(&v0, &v1, &a, 1);
  }

  // fused bias + LayerNorm (+ReLU)
#pragma unroll
  for (int i = 0; i < F; i += 4) {
    const float4 bb = *(const float4*)&bias[lane * F + i];
    acc[i + 0] += bb.x; acc[i + 1] += bb.y;
    acc[i + 2] += bb.z; acc[i + 3] += bb.w;
  }
  float sum = 0.f, sq = 0.f;
#pragma unroll
  for (int i = 0; i < F; ++i) { sum += acc[i]; sq += acc[i] * acc[i]; }
#pragma unroll
  for (int off = 1; off < 64; off <<= 1) {
    sum += __shfl_xor(sum, off);
    sq  += __shfl_xor(sq, off);
  }
  const float mu  = sum / HC;
  const float var = sq / HC - mu * mu;
  const float r   = rsqrtf(var + 1e-5f);
  float y[F];
#pragma unroll
  for (int i = 0; i < F; i += 4) {
    const float4 gg = *(const float4*)&lng[lane * F + i];
    const float4 bl = *(const float4*)&lnb[lane * F + i];
    y[i + 0] = (acc[i + 0] - mu) * r * gg.x + bl.x;
    y[i + 1] = (acc[i + 1] - mu) * r * gg.y + bl.y;
    y[i + 2] = (acc[i + 2] - mu) * r * gg.z + bl.z;
    y[i + 3] = (acc[i + 3] - mu) * r * gg.w + bl.w;
  }
  if constexpr (RELU) {
#pragma unroll
    for (int i = 0; i < F; ++i) y[i] = fmaxf(y[i], 0.f);
  }
  if constexpr (BFOUT) {
    unsigned short* op = &obf[(size_t)n * HC + lane * F];
    *(ushort4*)op = make_ushort4(f2b(y[0]), f2b(y[1]), f2b(y[2]), f2b(y[3]));
    if constexpr (F == 8)
      *(ushort4*)(op + 4) = make_ushort4(f2b(y[4]), f2b(y[5]), f2b(y[6]), f2b(y[7]));
  } else {
    float* op = &of32[(size_t)n * HC + lane * F];
    *(float4*)op = make_float4(y[0], y[1], y[2], y[3]);
    if constexpr (F == 8)
      *(float4*)(op + 4) = make_float4(y[4], y[5], y[6], y[7]);
  }
}

// ---------------------------------------------------------- global mean pool
__global__ __launch_bounds__(256)
void pool_partial(const unsigned short* __restrict__ x, const int* __restrict__ batch,
                  float* __restrict__ tmp, int* __restrict__ cnt, int Nn) {
  const int r0 = blockIdx.x * 64;
  const int rend = min(r0 + 64, Nn);
  const int t = threadIdx.x;
  float acc = 0.f;
  int cur = batch[r0];
  int seglen = 0;
  for (int r = r0; r < rend; ++r) {
    const int g = batch[r];
    if (g != cur) {
      unsafeAtomicAdd(&tmp[cur * 256 + t], acc);
      if (t == 0) atomicAdd(&cnt[cur], seglen);
      acc = 0.f; seglen = 0; cur = g;
    }
    acc += b2f(x[(size_t)r * 256 + t]);
    ++seglen;
  }
  unsafeAtomicAdd(&tmp[cur * 256 + t], acc);
  if (t == 0) atomicAdd(&cnt[cur], seglen);
}

__global__ __launch_bounds__(256)
void pool_final(const float* __restrict__ tmp, const int* __restrict__ cnt,
                float* __restrict__ out) {
  const int g = blockIdx.x;
  const int t = threadIdx.x;
  out[g * 256 + t] = tmp[g * 256 + t] / fmaxf((float)cnt[g], 1.f);
}

// ---------------------------------------------------------------------------
extern "C" void kernel_launch(void* const* d_in, const int* in_sizes, int n_in,
                              void* d_out, int out_size, void* d_ws, size_t ws_size,
                              hipStream_t stream) {
  const float* x    = (const float*)d_in[0];
  const int*   ei   = (const int*)d_in[1];
  const int*   batch= (const int*)d_in[2];
  const float* W1   = (const float*)d_in[3];
  const float* as1  = (const float*)d_in[4];
  const float* ad1  = (const float*)d_in[5];
  const float* b1   = (const float*)d_in[6];
  const float* g1   = (const float*)d_in[7];
  const float* be1  = (const float*)d_in[8];
  const float* W2   = (const float*)d_in[9];
  const float* as2  = (const float*)d_in[10];
  const float* ad2  = (const float*)d_in[11];
  const float* b2   = (const float*)d_in[12];
  const float* g2   = (const float*)d_in[13];
  const float* be2  = (const float*)d_in[14];

  const int N    = in_sizes[0] / 256;   // 50000
  const int E    = in_sizes[1] / 2;     // 400000
  const int Etot = E + N;
  const int Mpad = ((N + 127) / 128) * 128;   // 50048
  const int NB   = (N + 1023) / 1024;         // scan blocks (49)

  // ---------------- workspace layout ----------------
  float* ws = (float*)d_ws;
  unsigned short* out2 = (unsigned short*)ws;          // N*256 bf16
  unsigned short* A2bf = out2 + (size_t)N * 256;       // Mpad*512 bf16
  unsigned short* A1bf = A2bf;                         // Mpad*256 bf16 (dead before agg1 writes)
  unsigned short* h1bf = A2bf + (size_t)Mpad * 512;    // N*512 bf16 (h2bf aliases)
  unsigned short* W1T  = h1bf + (size_t)N * 512;       // 512*256 bf16
  unsigned short* W2T  = W1T + 512 * 256;              // 256*512 bf16
  // zeroed region: es1,ed1,s1 (N*4 each) + es2,ed2,s2 (N each) = N*15 floats
  float* es1 = (float*)(W2T + 512 * 256);
  float* ed1 = es1 + (size_t)N * 4;
  float* s1  = ed1 + (size_t)N * 4;
  float* es2 = s1  + (size_t)N * 4;
  float* ed2 = es2 + N;
  float* s2  = ed2 + N;
  int* count  = (int*)(s2 + N);                        // N
  int* rowptr = count + N;                             // N+1
  int* cursor = rowptr + N + 1;                        // N
  int* srcs   = cursor + N;                            // Etot
  int* dsts   = srcs + Etot;                           // Etot
  float* exCSR = (float*)(dsts + Etot);                // Etot*4
  float* ptmp = exCSR + (size_t)Etot * 4;              // 64*256
  int*   pcnt = (int*)(ptmp + 64 * 256);               // 64
  int*   bsum = pcnt + 64;                             // NB
  int*   boff = bsum + 64;                             // NB
  unsigned short* h2bf = h1bf;

  const int eb = (Etot + 255) / 256;

  // ---- zero-init ----
  hipMemsetAsync(es1, 0, (size_t)N * 15 * 4 + (size_t)N * 4, stream); // es/ed/s both layers + count
  hipMemsetAsync(ptmp, 0, (size_t)(64 * 256 + 64) * 4, stream);
  hipMemsetAsync(A2bf + (size_t)N * 512, 0, (size_t)(Mpad - N) * 512 * 2, stream);

  // ---- prep: x->bf16 pad + degree count, weight transposes ----
  prep_x_count<<<(Mpad * 64 + 255) / 256, 256, 0, stream>>>(
      x, A1bf, N, Mpad, ei, E, Etot, count);
  cvt_wts<<<(2 * 512 * 256 + 255) / 256, 256, 0, stream>>>(W1, W2, W1T, W2T);

  // ---- CSR build ----
  scan_blocksum<<<NB, 256, 0, stream>>>(count, bsum, N);
  scan_top<<<1, 64, 0, stream>>>(bsum, boff, &rowptr[N], NB);
  scan_apply<<<NB, 256, 0, stream>>>(count, boff, rowptr, cursor, N);
  csr_scatter<<<eb, 256, 0, stream>>>(ei, E, Etot, cursor, srcs, dsts);

  // ---- layer 1: GATConv(256 -> 4x128) + LN + ReLU ----
  gemm_bf16<8><<<dim3(4, Mpad / 128), 256, 0, stream>>>(
      A1bf, W1T, h1bf, N, 512, 256, as1, ad1, es1, ed1, 4, 7);
  ex_compute<4><<<eb, 256, 0, stream>>>(srcs, dsts, es1, ed1, exCSR, s1, Etot);
  gat_agg_ln<4, 128, true, true><<<(N + 3) / 4, 256, 0, stream>>>(
      rowptr, srcs, exCSR, s1, h1bf, b1, g1, be1, A2bf, nullptr, N);

  // ---- layer 2: GATConv(512 -> 1x256) + LN ----
  gemm_bf16<16><<<dim3(2, Mpad / 128), 256, 0, stream>>>(
      A2bf, W2T, h2bf, N, 256, 512, as2, ad2, es2, ed2, 1, 8);
  ex_compute<1><<<eb, 256, 0, stream>>>(srcs, dsts, es2, ed2, exCSR, s2, Etot);
  gat_agg_ln<1, 256, false, true><<<(N + 3) / 4, 256, 0, stream>>>(
      rowptr, srcs, exCSR, s2, h2bf, b2, g2, be2, out2, nullptr, N);

  // ---- global mean pool ----
  pool_partial<<<(N + 63) / 64, 256, 0, stream>>>(out2, batch, ptmp, pcnt, N);
  pool_final<<<64, 256, 0, stream>>>(ptmp, pcnt, (float*)d_out);
}

// Round 7
// 339.978 us; speedup vs baseline: 1.3402x; 1.3402x over previous
//
#include <hip/hip_runtime.h>
#include <hip/hip_bf16.h>
#include <cstdint>

#define LRELU_SLOPE 0.2f

typedef short bf16x8 __attribute__((ext_vector_type(8)));
typedef float f32x4  __attribute__((ext_vector_type(4)));

__device__ __forceinline__ float b2f(unsigned short u) {
  return __uint_as_float(((unsigned int)u) << 16);
}
__device__ __forceinline__ unsigned short f2b(float f) {  // RNE
  unsigned int u = __float_as_uint(f);
  return (unsigned short)((u + 0x7fff + ((u >> 16) & 1)) >> 16);
}

__device__ __forceinline__ void gload16(const void* g, void* l) {
  __builtin_amdgcn_global_load_lds(
      (const __attribute__((address_space(1))) unsigned int*)g,
      (__attribute__((address_space(3))) unsigned int*)l, 16, 0, 0);
}

// ---------------------------------------------- fused x->bf16 pad + csr_count
__global__ __launch_bounds__(256)
void prep_x_count(const float* __restrict__ x, unsigned short* __restrict__ o,
                  int M, int Mpad, const int* __restrict__ ei, int E, int Etot,
                  int* __restrict__ count) {
  const int i = blockIdx.x * 256 + threadIdx.x;
  if (i < Mpad * 64) {
    const int row = i >> 6;
    const int c4  = (i & 63) * 4;
    ushort4 v = make_ushort4(0, 0, 0, 0);
    if (row < M) {
      const float4 f = *(const float4*)&x[(size_t)row * 256 + c4];
      v = make_ushort4(f2b(f.x), f2b(f.y), f2b(f.z), f2b(f.w));
    }
    *(ushort4*)&o[(size_t)row * 256 + c4] = v;
  }
  if (i < Etot) {
    const int d = (i < E) ? ei[E + i] : (i - E);
    atomicAdd(&count[d], 1);
  }
}

// ------------------------------------- both weight transposes in one launch
__global__ __launch_bounds__(256)
void cvt_wts(const float* __restrict__ W1, const float* __restrict__ W2,
             unsigned short* __restrict__ W1T, unsigned short* __restrict__ W2T) {
  int j = blockIdx.x * 256 + threadIdx.x;
  if (j < 512 * 256) {
    const int n = j >> 8, k = j & 255;
    W1T[j] = f2b(W1[(size_t)k * 512 + n]);
  } else {
    j -= 512 * 256;
    const int n = j >> 9, k = j & 511;
    W2T[j] = f2b(W2[(size_t)k * 256 + n]);
  }
}

// ------------------------------------------------------------- CSR scan
__global__ __launch_bounds__(256)
void scan_blocksum(const int* __restrict__ count, int* __restrict__ bsum, int Nn) {
  const int i0 = blockIdx.x * 1024 + threadIdx.x * 4;
  int s = 0;
#pragma unroll
  for (int k = 0; k < 4; ++k) { const int i = i0 + k; if (i < Nn) s += count[i]; }
#pragma unroll
  for (int off = 1; off < 64; off <<= 1) s += __shfl_xor(s, off);
  __shared__ int ws[4];
  if ((threadIdx.x & 63) == 0) ws[threadIdx.x >> 6] = s;
  __syncthreads();
  if (threadIdx.x == 0) bsum[blockIdx.x] = ws[0] + ws[1] + ws[2] + ws[3];
}

__global__ __launch_bounds__(64)
void scan_top(const int* __restrict__ bsum, int* __restrict__ boff,
              int* __restrict__ rowptrN, int nb) {
  const int t = threadIdx.x;
  const int v = (t < nb) ? bsum[t] : 0;
  int incl = v;
#pragma unroll
  for (int off = 1; off < 64; off <<= 1) {
    const int u = __shfl_up(incl, off);
    if (t >= off) incl += u;
  }
  if (t < nb) boff[t] = incl - v;
  if (t == 63) *rowptrN = incl;
}

__global__ __launch_bounds__(256)
void scan_apply(const int* __restrict__ count, const int* __restrict__ boff,
                int* __restrict__ rowptr, int* __restrict__ cursor, int Nn) {
  const int t = threadIdx.x;
  const int lane = t & 63;
  const int w = t >> 6;
  const int i0 = blockIdx.x * 1024 + t * 4;
  int c[4]; int s = 0;
#pragma unroll
  for (int k = 0; k < 4; ++k) { const int i = i0 + k; c[k] = (i < Nn) ? count[i] : 0; s += c[k]; }
  int incl = s;
#pragma unroll
  for (int off = 1; off < 64; off <<= 1) {
    const int u = __shfl_up(incl, off);
    if (lane >= off) incl += u;
  }
  __shared__ int ws[4];
  if (lane == 63) ws[w] = incl;
  __syncthreads();
  int woff = 0;
  for (int k = 0; k < w; ++k) woff += ws[k];
  int base = boff[blockIdx.x] + woff + incl - s;
#pragma unroll
  for (int k = 0; k < 4; ++k) {
    const int i = i0 + k;
    if (i < Nn) { rowptr[i] = base; cursor[i] = base; base += c[k]; }
  }
}

__global__ __launch_bounds__(256)
void csr_scatter(const int* __restrict__ ei, int E, int Etot,
                 int* __restrict__ cursor, int* __restrict__ srcs,
                 int* __restrict__ dsts) {
  const int i = blockIdx.x * 256 + threadIdx.x;
  if (i >= Etot) return;
  const int s = (i < E) ? ei[i]     : (i - E);
  const int d = (i < E) ? ei[E + i] : (i - E);
  const int pos = atomicAdd(&cursor[d], 1);
  srcs[pos] = s;
  dsts[pos] = d;
}

// ------------------------------- bf16 MFMA GEMM + fused attention-logit dots
template<int KSTEPS>
__global__ __launch_bounds__(256)
void gemm_bf16(const unsigned short* __restrict__ A,
               const unsigned short* __restrict__ BT,
               unsigned short* __restrict__ C, int M, int Nn, int K,
               const float* __restrict__ asrc, const float* __restrict__ adst,
               float* __restrict__ es, float* __restrict__ ed,
               int H, int lgC) {
  __shared__ unsigned short As[2][128 * 32];
  __shared__ unsigned short Bs[2][128 * 32];
  const int tid  = threadIdx.x;
  const int lane = tid & 63;
  const int wave = tid >> 6;
  const int wm = wave >> 1, wn = wave & 1;
  const int brow = blockIdx.y * 128;
  const int bcol = blockIdx.x * 128;
  const int srow  = tid >> 2;
  const int sslot = tid & 3;
  const int sswz  = sslot ^ (srow & 3);
  const size_t aBase0 = (size_t)(brow + srow) * K + sswz * 8;
  const size_t aBase1 = (size_t)(brow + 64 + srow) * K + sswz * 8;
  const size_t bBase0 = (size_t)(bcol + srow) * K + sswz * 8;
  const size_t bBase1 = (size_t)(bcol + 64 + srow) * K + sswz * 8;
  const int ldsOff0 = srow * 32 + sslot * 8;
  const int ldsOff1 = (64 + srow) * 32 + sslot * 8;

  f32x4 acc[4][4] = {};
  const int u   = lane >> 4;
  const int r15 = lane & 15;
  const int sw  = u ^ (r15 & 3);

  auto stage = [&](int buf, int ks) {
    const int k0 = ks * 32;
    gload16(A + aBase0 + k0, &As[buf][ldsOff0]);
    gload16(A + aBase1 + k0, &As[buf][ldsOff1]);
    gload16(BT + bBase0 + k0, &Bs[buf][ldsOff0]);
    gload16(BT + bBase1 + k0, &Bs[buf][ldsOff1]);
  };

  stage(0, 0);
  asm volatile("s_waitcnt vmcnt(0)" ::: "memory");
  __syncthreads();
  int cur = 0;
#pragma unroll
  for (int ks = 0; ks < KSTEPS; ++ks) {
    if (ks + 1 < KSTEPS) stage(cur ^ 1, ks + 1);
    bf16x8 af[4], bfv[4];
#pragma unroll
    for (int m = 0; m < 4; ++m) {
      const int row = wm * 64 + m * 16 + r15;
      af[m]  = *(const bf16x8*)&As[cur][row * 32 + sw * 8];
      const int col = wn * 64 + m * 16 + r15;
      bfv[m] = *(const bf16x8*)&Bs[cur][col * 32 + sw * 8];
    }
#pragma unroll
    for (int m = 0; m < 4; ++m)
#pragma unroll
      for (int n = 0; n < 4; ++n)
        acc[m][n] = __builtin_amdgcn_mfma_f32_16x16x32_bf16(
            af[m], bfv[n], acc[m][n], 0, 0, 0);
    if (ks + 1 < KSTEPS) {
      asm volatile("s_waitcnt vmcnt(0)" ::: "memory");
      __syncthreads();
      cur ^= 1;
    }
  }
#pragma unroll
  for (int m = 0; m < 4; ++m) {
    const int r0 = brow + wm * 64 + m * 16 + u * 4;
#pragma unroll
    for (int n = 0; n < 4; ++n) {
      const int cc = bcol + wn * 64 + n * 16 + r15;
#pragma unroll
      for (int r = 0; r < 4; ++r)
        if (r0 + r < M) C[(size_t)(r0 + r) * Nn + cc] = f2b(acc[m][n][r]);
    }
  }
  // fused attention logits: es/ed[row,head] += sum_cols h*a
  const int head = bcol >> lgC;
  float asv[4], adv[4];
#pragma unroll
  for (int n = 0; n < 4; ++n) {
    const int cc = bcol + wn * 64 + n * 16 + r15;
    asv[n] = asrc[cc];
    adv[n] = adst[cc];
  }
#pragma unroll
  for (int m = 0; m < 4; ++m) {
#pragma unroll
    for (int r = 0; r < 4; ++r) {
      float pes = 0.f, ped = 0.f;
#pragma unroll
      for (int n = 0; n < 4; ++n) {
        pes = fmaf(acc[m][n][r], asv[n], pes);
        ped = fmaf(acc[m][n][r], adv[n], ped);
      }
#pragma unroll
      for (int off = 1; off < 16; off <<= 1) {
        pes += __shfl_xor(pes, off);
        ped += __shfl_xor(ped, off);
      }
      if (r15 == 0) {
        const int row = brow + wm * 64 + m * 16 + u * 4 + r;
        if (row < M) {
          unsafeAtomicAdd(&es[row * H + head], pes);
          unsafeAtomicAdd(&ed[row * H + head], ped);
        }
      }
    }
  }
}

// ------------------- edge-parallel softmax numerator (CSR order), NO atomics
template<int H>
__global__ __launch_bounds__(256)
void ex_compute(const int* __restrict__ srcs, const int* __restrict__ dsts,
                const float* __restrict__ es, const float* __restrict__ ed,
                float* __restrict__ exCSR, int Etot) {
  const int p = blockIdx.x * 256 + threadIdx.x;
  if (p >= Etot) return;
  const int sN = srcs[p], dN = dsts[p];
  if constexpr (H == 4) {
    const float4 a = *(const float4*)&es[sN * 4];
    const float4 b = *(const float4*)&ed[dN * 4];
    float e0 = a.x + b.x, e1 = a.y + b.y, e2 = a.z + b.z, e3 = a.w + b.w;
    e0 = (e0 > 0.f) ? e0 : LRELU_SLOPE * e0;
    e1 = (e1 > 0.f) ? e1 : LRELU_SLOPE * e1;
    e2 = (e2 > 0.f) ? e2 : LRELU_SLOPE * e2;
    e3 = (e3 > 0.f) ? e3 : LRELU_SLOPE * e3;
    *(float4*)&exCSR[p * 4] =
        make_float4(__expf(e0), __expf(e1), __expf(e2), __expf(e3));
  } else {
    float e = es[sN] + ed[dN];
    e = (e > 0.f) ? e : LRELU_SLOPE * e;
    exCSR[p] = __expf(e);
  }
}

// ---------------------- gather GAT aggregation + fused bias/LayerNorm(/ReLU)
// one wave per node; denom from coalesced exCSR stream; 4-deep gather pipeline.
template<int H, int C, bool RELU, bool BFOUT>
__global__ __launch_bounds__(256)
void gat_agg_ln(const int* __restrict__ rowptr, const int* __restrict__ srcs,
                const float* __restrict__ exCSR,
                const unsigned short* __restrict__ h,
                const float* __restrict__ bias, const float* __restrict__ lng,
                const float* __restrict__ lnb, unsigned short* __restrict__ obf,
                float* __restrict__ of32, int Nn) {
  constexpr int HC = H * C;
  constexpr int F  = HC / 64;          // 8 (layer1) or 4 (layer2)
  const int wave = threadIdx.x >> 6;
  const int lane = threadIdx.x & 63;
  const int n = blockIdx.x * 4 + wave;
  if (n >= Nn) return;
  const int beg = rowptr[n];
  const int deg = rowptr[n + 1] - beg;
  const int hl = (lane * F) / C;

  // pass 0: per-head denominator — coalesced stream over own exCSR segment
  float dsum = 0.f;
  if constexpr (H == 4) {
    for (int it = lane; it < deg * 4; it += 64) dsum += exCSR[beg * 4 + it];
#pragma unroll
    for (int off = 4; off < 64; off <<= 1) dsum += __shfl_xor(dsum, off);
    dsum = __shfl(dsum, hl);      // lane hl holds denom[head hl]
  } else {
    for (int it = lane; it < deg; it += 64) dsum += exCSR[beg + it];
#pragma unroll
    for (int off = 1; off < 64; off <<= 1) dsum += __shfl_xor(dsum, off);
  }
  const float inv_s = 1.0f / (dsum + 1e-16f);

  float acc[F];
#pragma unroll
  for (int i = 0; i < F; ++i) acc[i] = 0.f;

  auto fma_rows = [&](const ushort4* v0, const ushort4* v1, const float* a, int cnt) {
    for (int q = 0; q < cnt; ++q) {
      acc[0] = fmaf(b2f(v0[q].x), a[q], acc[0]);
      acc[1] = fmaf(b2f(v0[q].y), a[q], acc[1]);
      acc[2] = fmaf(b2f(v0[q].z), a[q], acc[2]);
      acc[3] = fmaf(b2f(v0[q].w), a[q], acc[3]);
      if constexpr (F == 8) {
        acc[4] = fmaf(b2f(v1[q].x), a[q], acc[4]);
        acc[5] = fmaf(b2f(v1[q].y), a[q], acc[5]);
        acc[6] = fmaf(b2f(v1[q].z), a[q], acc[6]);
        acc[7] = fmaf(b2f(v1[q].w), a[q], acc[7]);
      }
    }
  };

  int j = 0;
  for (; j + 4 <= deg; j += 4) {
    int s4[4];
    float a4[4];
#pragma unroll
    for (int q = 0; q < 4; ++q) s4[q] = srcs[beg + j + q];
#pragma unroll
    for (int q = 0; q < 4; ++q) a4[q] = exCSR[(beg + j + q) * H + hl] * inv_s;
    ushort4 v0[4], v1[4];
#pragma unroll
    for (int q = 0; q < 4; ++q) {
      const unsigned short* hp = &h[(size_t)s4[q] * HC + lane * F];
      v0[q] = *(const ushort4*)hp;
      if constexpr (F == 8) v1[q] = *(const ushort4*)(hp + 4);
    }
    fma_rows(v0, v1, a4, 4);
  }
  for (; j < deg; ++j) {
    const int src = srcs[beg + j];
    const float a = exCSR[(beg + j) * H + hl] * inv_s;
    const unsigned short* hp = &h[(size_t)src * HC + lane * F];
    ushort4 v0 = *(const ushort4*)hp, v1;
    if constexpr (F == 8) v1 = *(const ushort4*)(hp + 4);
    fma_rows(&v0, &v1, &a, 1);
  }

  // fused bias + LayerNorm (+ReLU)
#pragma unroll
  for (int i = 0; i < F; i += 4) {
    const float4 bb = *(const float4*)&bias[lane * F + i];
    acc[i + 0] += bb.x; acc[i + 1] += bb.y;
    acc[i + 2] += bb.z; acc[i + 3] += bb.w;
  }
  float sum = 0.f, sq = 0.f;
#pragma unroll
  for (int i = 0; i < F; ++i) { sum += acc[i]; sq += acc[i] * acc[i]; }
#pragma unroll
  for (int off = 1; off < 64; off <<= 1) {
    sum += __shfl_xor(sum, off);
    sq  += __shfl_xor(sq, off);
  }
  const float mu  = sum / HC;
  const float var = sq / HC - mu * mu;
  const float r   = rsqrtf(var + 1e-5f);
  float y[F];
#pragma unroll
  for (int i = 0; i < F; i += 4) {
    const float4 gg = *(const float4*)&lng[lane * F + i];
    const float4 bl = *(const float4*)&lnb[lane * F + i];
    y[i + 0] = (acc[i + 0] - mu) * r * gg.x + bl.x;
    y[i + 1] = (acc[i + 1] - mu) * r * gg.y + bl.y;
    y[i + 2] = (acc[i + 2] - mu) * r * gg.z + bl.z;
    y[i + 3] = (acc[i + 3] - mu) * r * gg.w + bl.w;
  }
  if constexpr (RELU) {
#pragma unroll
    for (int i = 0; i < F; ++i) y[i] = fmaxf(y[i], 0.f);
  }
  if constexpr (BFOUT) {
    unsigned short* op = &obf[(size_t)n * HC + lane * F];
    *(ushort4*)op = make_ushort4(f2b(y[0]), f2b(y[1]), f2b(y[2]), f2b(y[3]));
    if constexpr (F == 8)
      *(ushort4*)(op + 4) = make_ushort4(f2b(y[4]), f2b(y[5]), f2b(y[6]), f2b(y[7]));
  } else {
    float* op = &of32[(size_t)n * HC + lane * F];
    *(float4*)op = make_float4(y[0], y[1], y[2], y[3]);
    if constexpr (F == 8)
      *(float4*)(op + 4) = make_float4(y[4], y[5], y[6], y[7]);
  }
}

// ---------------------------------------------------------- global mean pool
__global__ __launch_bounds__(256)
void pool_partial(const unsigned short* __restrict__ x, const int* __restrict__ batch,
                  float* __restrict__ tmp, int* __restrict__ cnt, int Nn) {
  const int r0 = blockIdx.x * 64;
  const int rend = min(r0 + 64, Nn);
  const int t = threadIdx.x;
  float acc = 0.f;
  int cur = batch[r0];
  int seglen = 0;
  for (int r = r0; r < rend; ++r) {
    const int g = batch[r];
    if (g != cur) {
      unsafeAtomicAdd(&tmp[cur * 256 + t], acc);
      if (t == 0) atomicAdd(&cnt[cur], seglen);
      acc = 0.f; seglen = 0; cur = g;
    }
    acc += b2f(x[(size_t)r * 256 + t]);
    ++seglen;
  }
  unsafeAtomicAdd(&tmp[cur * 256 + t], acc);
  if (t == 0) atomicAdd(&cnt[cur], seglen);
}

__global__ __launch_bounds__(256)
void pool_final(const float* __restrict__ tmp, const int* __restrict__ cnt,
                float* __restrict__ out) {
  const int g = blockIdx.x;
  const int t = threadIdx.x;
  out[g * 256 + t] = tmp[g * 256 + t] / fmaxf((float)cnt[g], 1.f);
}

// ---------------------------------------------------------------------------
extern "C" void kernel_launch(void* const* d_in, const int* in_sizes, int n_in,
                              void* d_out, int out_size, void* d_ws, size_t ws_size,
                              hipStream_t stream) {
  const float* x    = (const float*)d_in[0];
  const int*   ei   = (const int*)d_in[1];
  const int*   batch= (const int*)d_in[2];
  const float* W1   = (const float*)d_in[3];
  const float* as1  = (const float*)d_in[4];
  const float* ad1  = (const float*)d_in[5];
  const float* b1   = (const float*)d_in[6];
  const float* g1   = (const float*)d_in[7];
  const float* be1  = (const float*)d_in[8];
  const float* W2   = (const float*)d_in[9];
  const float* as2  = (const float*)d_in[10];
  const float* ad2  = (const float*)d_in[11];
  const float* b2   = (const float*)d_in[12];
  const float* g2   = (const float*)d_in[13];
  const float* be2  = (const float*)d_in[14];

  const int N    = in_sizes[0] / 256;   // 50000
  const int E    = in_sizes[1] / 2;     // 400000
  const int Etot = E + N;
  const int Mpad = ((N + 127) / 128) * 128;   // 50048
  const int NB   = (N + 1023) / 1024;         // scan blocks (49)

  // ---------------- workspace layout ----------------
  float* ws = (float*)d_ws;
  unsigned short* out2 = (unsigned short*)ws;          // N*256 bf16
  unsigned short* A2bf = out2 + (size_t)N * 256;       // Mpad*512 bf16
  unsigned short* A1bf = A2bf;                         // Mpad*256 bf16
  unsigned short* h1bf = A2bf + (size_t)Mpad * 512;    // N*512 bf16 (h2bf aliases)
  unsigned short* W1T  = h1bf + (size_t)N * 512;       // 512*256 bf16
  unsigned short* W2T  = W1T + 512 * 256;              // 256*512 bf16
  float* es1 = (float*)(W2T + 512 * 256);              // N*4
  float* ed1 = es1 + (size_t)N * 4;                    // N*4
  float* es2 = ed1 + (size_t)N * 4;                    // N
  float* ed2 = es2 + N;                                // N
  int* count  = (int*)(ed2 + N);                       // N
  int* rowptr = count + N;                             // N+1 (+pad)
  int* cursor = rowptr + N + 4;                        // N  (pad keeps 16B align)
  int* srcs   = cursor + N;                            // Etot
  int* dsts   = srcs + Etot;                           // Etot
  float* exCSR = (float*)(dsts + Etot);                // Etot*4
  float* ptmp = exCSR + (size_t)Etot * 4;              // 64*256
  int*   pcnt = (int*)(ptmp + 64 * 256);               // 64
  int*   bsum = pcnt + 64;                             // NB
  int*   boff = bsum + 64;                             // NB
  unsigned short* h2bf = h1bf;

  const int eb = (Etot + 255) / 256;

  // ---- zero-init: es1,ed1,es2,ed2 (10N f32) + count (N int) contiguous ----
  hipMemsetAsync(es1, 0, (size_t)N * 11 * 4, stream);
  hipMemsetAsync(ptmp, 0, (size_t)(64 * 256 + 64) * 4, stream);
  hipMemsetAsync(A2bf + (size_t)N * 512, 0, (size_t)(Mpad - N) * 512 * 2, stream);

  // ---- prep: x->bf16 pad + degree count, weight transposes ----
  prep_x_count<<<(Mpad * 64 + 255) / 256, 256, 0, stream>>>(
      x, A1bf, N, Mpad, ei, E, Etot, count);
  cvt_wts<<<(2 * 512 * 256 + 255) / 256, 256, 0, stream>>>(W1, W2, W1T, W2T);

  // ---- CSR build ----
  scan_blocksum<<<NB, 256, 0, stream>>>(count, bsum, N);
  scan_top<<<1, 64, 0, stream>>>(bsum, boff, &rowptr[N], NB);
  scan_apply<<<NB, 256, 0, stream>>>(count, boff, rowptr, cursor, N);
  csr_scatter<<<eb, 256, 0, stream>>>(ei, E, Etot, cursor, srcs, dsts);

  // ---- layer 1: GATConv(256 -> 4x128) + LN + ReLU ----
  gemm_bf16<8><<<dim3(4, Mpad / 128), 256, 0, stream>>>(
      A1bf, W1T, h1bf, N, 512, 256, as1, ad1, es1, ed1, 4, 7);
  ex_compute<4><<<eb, 256, 0, stream>>>(srcs, dsts, es1, ed1, exCSR, Etot);
  gat_agg_ln<4, 128, true, true><<<(N + 3) / 4, 256, 0, stream>>>(
      rowptr, srcs, exCSR, h1bf, b1, g1, be1, A2bf, nullptr, N);

  // ---- layer 2: GATConv(512 -> 1x256) + LN ----
  gemm_bf16<16><<<dim3(2, Mpad / 128), 256, 0, stream>>>(
      A2bf, W2T, h2bf, N, 256, 512, as2, ad2, es2, ed2, 1, 8);
  ex_compute<1><<<eb, 256, 0, stream>>>(srcs, dsts, es2, ed2, exCSR, Etot);
  gat_agg_ln<1, 256, false, true><<<(N + 3) / 4, 256, 0, stream>>>(
      rowptr, srcs, exCSR, h2bf, b2, g2, be2, out2, nullptr, N);

  // ---- global mean pool ----
  pool_partial<<<(N + 63) / 64, 256, 0, stream>>>(out2, batch, ptmp, pcnt, N);
  pool_final<<<64, 256, 0, stream>>>(ptmp, pcnt, (float*)d_out);
}

// Round 8
// 333.928 us; speedup vs baseline: 1.3645x; 1.0181x over previous
//
#include <hip/hip_runtime.h>
#include <hip/hip_bf16.h>
#include <cstdint>

#define LRELU_SLOPE 0.2f

typedef short bf16x8 __attribute__((ext_vector_type(8)));
typedef float f32x4  __attribute__((ext_vector_type(4)));

__device__ __forceinline__ float b2f(unsigned short u) {
  return __uint_as_float(((unsigned int)u) << 16);
}
__device__ __forceinline__ unsigned short f2b(float f) {  // RNE
  unsigned int u = __float_as_uint(f);
  return (unsigned short)((u + 0x7fff + ((u >> 16) & 1)) >> 16);
}

__device__ __forceinline__ void gload16(const void* g, void* l) {
  __builtin_amdgcn_global_load_lds(
      (const __attribute__((address_space(1))) unsigned int*)g,
      (__attribute__((address_space(3))) unsigned int*)l, 16, 0, 0);
}

// ---------------------------------------------- fused x->bf16 pad + csr_count
__global__ __launch_bounds__(256)
void prep_x_count(const float* __restrict__ x, unsigned short* __restrict__ o,
                  int M, int Mpad, const int* __restrict__ ei, int E, int Etot,
                  int* __restrict__ count) {
  const int i = blockIdx.x * 256 + threadIdx.x;
  if (i < Mpad * 64) {
    const int row = i >> 6;
    const int c4  = (i & 63) * 4;
    ushort4 v = make_ushort4(0, 0, 0, 0);
    if (row < M) {
      const float4 f = *(const float4*)&x[(size_t)row * 256 + c4];
      v = make_ushort4(f2b(f.x), f2b(f.y), f2b(f.z), f2b(f.w));
    }
    *(ushort4*)&o[(size_t)row * 256 + c4] = v;
  }
  if (i < Etot) {
    const int d = (i < E) ? ei[E + i] : (i - E);
    atomicAdd(&count[d], 1);
  }
}

// ------------------------------------- both weight transposes in one launch
__global__ __launch_bounds__(256)
void cvt_wts(const float* __restrict__ W1, const float* __restrict__ W2,
             unsigned short* __restrict__ W1T, unsigned short* __restrict__ W2T) {
  int j = blockIdx.x * 256 + threadIdx.x;
  if (j < 512 * 256) {
    const int n = j >> 8, k = j & 255;
    W1T[j] = f2b(W1[(size_t)k * 512 + n]);
  } else {
    j -= 512 * 256;
    const int n = j >> 9, k = j & 511;
    W2T[j] = f2b(W2[(size_t)k * 256 + n]);
  }
}

// ------------------------------------------------------------- CSR scan
__global__ __launch_bounds__(256)
void scan_blocksum(const int* __restrict__ count, int* __restrict__ bsum, int Nn) {
  const int i0 = blockIdx.x * 1024 + threadIdx.x * 4;
  int s = 0;
#pragma unroll
  for (int k = 0; k < 4; ++k) { const int i = i0 + k; if (i < Nn) s += count[i]; }
#pragma unroll
  for (int off = 1; off < 64; off <<= 1) s += __shfl_xor(s, off);
  __shared__ int ws[4];
  if ((threadIdx.x & 63) == 0) ws[threadIdx.x >> 6] = s;
  __syncthreads();
  if (threadIdx.x == 0) bsum[blockIdx.x] = ws[0] + ws[1] + ws[2] + ws[3];
}

__global__ __launch_bounds__(64)
void scan_top(const int* __restrict__ bsum, int* __restrict__ boff,
              int* __restrict__ rowptrN, int nb) {
  const int t = threadIdx.x;
  const int v = (t < nb) ? bsum[t] : 0;
  int incl = v;
#pragma unroll
  for (int off = 1; off < 64; off <<= 1) {
    const int u = __shfl_up(incl, off);
    if (t >= off) incl += u;
  }
  if (t < nb) boff[t] = incl - v;
  if (t == 63) *rowptrN = incl;
}

__global__ __launch_bounds__(256)
void scan_apply(const int* __restrict__ count, const int* __restrict__ boff,
                int* __restrict__ rowptr, int* __restrict__ cursor, int Nn) {
  const int t = threadIdx.x;
  const int lane = t & 63;
  const int w = t >> 6;
  const int i0 = blockIdx.x * 1024 + t * 4;
  int c[4]; int s = 0;
#pragma unroll
  for (int k = 0; k < 4; ++k) { const int i = i0 + k; c[k] = (i < Nn) ? count[i] : 0; s += c[k]; }
  int incl = s;
#pragma unroll
  for (int off = 1; off < 64; off <<= 1) {
    const int u = __shfl_up(incl, off);
    if (lane >= off) incl += u;
  }
  __shared__ int ws[4];
  if (lane == 63) ws[w] = incl;
  __syncthreads();
  int woff = 0;
  for (int k = 0; k < w; ++k) woff += ws[k];
  int base = boff[blockIdx.x] + woff + incl - s;
#pragma unroll
  for (int k = 0; k < 4; ++k) {
    const int i = i0 + k;
    if (i < Nn) { rowptr[i] = base; cursor[i] = base; base += c[k]; }
  }
}

__global__ __launch_bounds__(256)
void csr_scatter(const int* __restrict__ ei, int E, int Etot,
                 int* __restrict__ cursor, int* __restrict__ srcs,
                 int* __restrict__ dsts) {
  const int i = blockIdx.x * 256 + threadIdx.x;
  if (i >= Etot) return;
  const int s = (i < E) ? ei[i]     : (i - E);
  const int d = (i < E) ? ei[E + i] : (i - E);
  const int pos = atomicAdd(&cursor[d], 1);
  srcs[pos] = s;
  dsts[pos] = d;
}

// ------------------------------- bf16 MFMA GEMM + fused attention-logit dots
// 3-buffer LDS pipeline, 2 tiles prefetched ahead, counted vmcnt (never 0 in
// steady state), raw s_barrier (no compiler full-drain).
template<int KSTEPS>
__global__ __launch_bounds__(256)
void gemm_bf16(const unsigned short* __restrict__ A,
               const unsigned short* __restrict__ BT,
               unsigned short* __restrict__ C, int M, int Nn, int K,
               const float* __restrict__ asrc, const float* __restrict__ adst,
               float* __restrict__ es, float* __restrict__ ed,
               int H, int lgC, int esPart) {
  __shared__ unsigned short As[3][128 * 32];
  __shared__ unsigned short Bs[3][128 * 32];
  const int tid  = threadIdx.x;
  const int lane = tid & 63;
  const int wave = tid >> 6;
  const int wm = wave >> 1, wn = wave & 1;
  const int brow = blockIdx.y * 128;
  const int bcol = blockIdx.x * 128;
  const int srow  = tid >> 2;
  const int sslot = tid & 3;
  const int sswz  = sslot ^ (srow & 3);
  const size_t aBase0 = (size_t)(brow + srow) * K + sswz * 8;
  const size_t aBase1 = (size_t)(brow + 64 + srow) * K + sswz * 8;
  const size_t bBase0 = (size_t)(bcol + srow) * K + sswz * 8;
  const size_t bBase1 = (size_t)(bcol + 64 + srow) * K + sswz * 8;
  const int ldsOff0 = srow * 32 + sslot * 8;
  const int ldsOff1 = (64 + srow) * 32 + sslot * 8;
  es += (size_t)blockIdx.x * esPart;
  ed += (size_t)blockIdx.x * esPart;

  f32x4 acc[4][4] = {};
  const int u   = lane >> 4;
  const int r15 = lane & 15;
  const int sw  = u ^ (r15 & 3);

  auto stage = [&](int buf, int ks) {
    const int k0 = ks * 32;
    gload16(A + aBase0 + k0, &As[buf][ldsOff0]);
    gload16(A + aBase1 + k0, &As[buf][ldsOff1]);
    gload16(BT + bBase0 + k0, &Bs[buf][ldsOff0]);
    gload16(BT + bBase1 + k0, &Bs[buf][ldsOff1]);
  };

  stage(0, 0);
  stage(1, 1);
#pragma unroll
  for (int ks = 0; ks < KSTEPS; ++ks) {
    // wait for tile ks (issued 2 steps ago); keep tile ks+1 in flight
    if (ks + 1 < KSTEPS)
      asm volatile("s_waitcnt vmcnt(4)" ::: "memory");
    else
      asm volatile("s_waitcnt vmcnt(0)" ::: "memory");
    __builtin_amdgcn_s_barrier();   // also fences compute(ks-1) before overwrite
    if (ks + 2 < KSTEPS) stage((ks + 2) % 3, ks + 2);
    const int cur = ks % 3;
    bf16x8 af[4], bfv[4];
#pragma unroll
    for (int m = 0; m < 4; ++m) {
      const int row = wm * 64 + m * 16 + r15;
      af[m]  = *(const bf16x8*)&As[cur][row * 32 + sw * 8];
      const int col = wn * 64 + m * 16 + r15;
      bfv[m] = *(const bf16x8*)&Bs[cur][col * 32 + sw * 8];
    }
#pragma unroll
    for (int m = 0; m < 4; ++m)
#pragma unroll
      for (int n = 0; n < 4; ++n)
        acc[m][n] = __builtin_amdgcn_mfma_f32_16x16x32_bf16(
            af[m], bfv[n], acc[m][n], 0, 0, 0);
  }
  // ---- C write ----
#pragma unroll
  for (int m = 0; m < 4; ++m) {
    const int r0 = brow + wm * 64 + m * 16 + u * 4;
#pragma unroll
    for (int n = 0; n < 4; ++n) {
      const int cc = bcol + wn * 64 + n * 16 + r15;
#pragma unroll
      for (int r = 0; r < 4; ++r)
        if (r0 + r < M) C[(size_t)(r0 + r) * Nn + cc] = f2b(acc[m][n][r]);
    }
  }
  // ---- fused attention logits: es/ed[row,head] += sum_cols h*a ----
  const int head = bcol >> lgC;
  float asv[4], adv[4];
#pragma unroll
  for (int n = 0; n < 4; ++n) {
    const int cc = bcol + wn * 64 + n * 16 + r15;
    asv[n] = asrc[cc];
    adv[n] = adst[cc];
  }
#pragma unroll
  for (int m = 0; m < 4; ++m) {
#pragma unroll
    for (int r = 0; r < 4; ++r) {
      float pes = 0.f, ped = 0.f;
#pragma unroll
      for (int n = 0; n < 4; ++n) {
        pes = fmaf(acc[m][n][r], asv[n], pes);
        ped = fmaf(acc[m][n][r], adv[n], ped);
      }
#pragma unroll
      for (int off = 1; off < 16; off <<= 1) {
        pes += __shfl_xor(pes, off);
        ped += __shfl_xor(ped, off);
      }
      if (r15 == 0) {
        const int row = brow + wm * 64 + m * 16 + u * 4 + r;
        if (row < M) {
          unsafeAtomicAdd(&es[row * H + head], pes);
          unsafeAtomicAdd(&ed[row * H + head], ped);
        }
      }
    }
  }
}

// ------------------- edge-parallel softmax numerator (CSR order), NO atomics
template<int H>
__global__ __launch_bounds__(256)
void ex_compute(const int* __restrict__ srcs, const int* __restrict__ dsts,
                const float* __restrict__ es, const float* __restrict__ ed,
                float* __restrict__ exCSR, int Etot, int pN) {
  const int p = blockIdx.x * 256 + threadIdx.x;
  if (p >= Etot) return;
  const int sN = srcs[p], dN = dsts[p];
  if constexpr (H == 4) {
    const float4 a = *(const float4*)&es[sN * 4];
    const float4 b = *(const float4*)&ed[dN * 4];
    float e0 = a.x + b.x, e1 = a.y + b.y, e2 = a.z + b.z, e3 = a.w + b.w;
    e0 = (e0 > 0.f) ? e0 : LRELU_SLOPE * e0;
    e1 = (e1 > 0.f) ? e1 : LRELU_SLOPE * e1;
    e2 = (e2 > 0.f) ? e2 : LRELU_SLOPE * e2;
    e3 = (e3 > 0.f) ? e3 : LRELU_SLOPE * e3;
    *(float4*)&exCSR[p * 4] =
        make_float4(__expf(e0), __expf(e1), __expf(e2), __expf(e3));
  } else {
    float e = (es[sN] + es[pN + sN]) + (ed[dN] + ed[pN + dN]);
    e = (e > 0.f) ? e : LRELU_SLOPE * e;
    exCSR[p] = __expf(e);
  }
}

// ---------------------- gather GAT aggregation + fused bias/LayerNorm(/ReLU)
template<int H, int C, bool RELU, bool BFOUT>
__global__ __launch_bounds__(256)
void gat_agg_ln(const int* __restrict__ rowptr, const int* __restrict__ srcs,
                const float* __restrict__ exCSR,
                const unsigned short* __restrict__ h,
                const float* __restrict__ bias, const float* __restrict__ lng,
                const float* __restrict__ lnb, unsigned short* __restrict__ obf,
                float* __restrict__ of32, int Nn) {
  constexpr int HC = H * C;
  constexpr int F  = HC / 64;
  const int wave = threadIdx.x >> 6;
  const int lane = threadIdx.x & 63;
  const int n = blockIdx.x * 4 + wave;
  if (n >= Nn) return;
  const int beg = rowptr[n];
  const int deg = rowptr[n + 1] - beg;
  const int hl = (lane * F) / C;

  float dsum = 0.f;
  if constexpr (H == 4) {
    for (int it = lane; it < deg * 4; it += 64) dsum += exCSR[beg * 4 + it];
#pragma unroll
    for (int off = 4; off < 64; off <<= 1) dsum += __shfl_xor(dsum, off);
    dsum = __shfl(dsum, hl);
  } else {
    for (int it = lane; it < deg; it += 64) dsum += exCSR[beg + it];
#pragma unroll
    for (int off = 1; off < 64; off <<= 1) dsum += __shfl_xor(dsum, off);
  }
  const float inv_s = 1.0f / (dsum + 1e-16f);

  float acc[F];
#pragma unroll
  for (int i = 0; i < F; ++i) acc[i] = 0.f;

  auto fma_rows = [&](const ushort4* v0, const ushort4* v1, const float* a, int cnt) {
    for (int q = 0; q < cnt; ++q) {
      acc[0] = fmaf(b2f(v0[q].x), a[q], acc[0]);
      acc[1] = fmaf(b2f(v0[q].y), a[q], acc[1]);
      acc[2] = fmaf(b2f(v0[q].z), a[q], acc[2]);
      acc[3] = fmaf(b2f(v0[q].w), a[q], acc[3]);
      if constexpr (F == 8) {
        acc[4] = fmaf(b2f(v1[q].x), a[q], acc[4]);
        acc[5] = fmaf(b2f(v1[q].y), a[q], acc[5]);
        acc[6] = fmaf(b2f(v1[q].z), a[q], acc[6]);
        acc[7] = fmaf(b2f(v1[q].w), a[q], acc[7]);
      }
    }
  };

  int j = 0;
  for (; j + 4 <= deg; j += 4) {
    int s4[4];
    float a4[4];
#pragma unroll
    for (int q = 0; q < 4; ++q) s4[q] = srcs[beg + j + q];
#pragma unroll
    for (int q = 0; q < 4; ++q) a4[q] = exCSR[(beg + j + q) * H + hl] * inv_s;
    ushort4 v0[4], v1[4];
#pragma unroll
    for (int q = 0; q < 4; ++q) {
      const unsigned short* hp = &h[(size_t)s4[q] * HC + lane * F];
      v0[q] = *(const ushort4*)hp;
      if constexpr (F == 8) v1[q] = *(const ushort4*)(hp + 4);
    }
    fma_rows(v0, v1, a4, 4);
  }
  for (; j < deg; ++j) {
    const int src = srcs[beg + j];
    const float a = exCSR[(beg + j) * H + hl] * inv_s;
    const unsigned short* hp = &h[(size_t)src * HC + lane * F];
    ushort4 v0 = *(const ushort4*)hp, v1;
    if constexpr (F == 8) v1 = *(const ushort4*)(hp + 4);
    fma_rows(&v0, &v1, &a, 1);
  }

#pragma unroll
  for (int i = 0; i < F; i += 4) {
    const float4 bb = *(const float4*)&bias[lane * F + i];
    acc[i + 0] += bb.x; acc[i + 1] += bb.y;
    acc[i + 2] += bb.z; acc[i + 3] += bb.w;
  }
  float sum = 0.f, sq = 0.f;
#pragma unroll
  for (int i = 0; i < F; ++i) { sum += acc[i]; sq += acc[i] * acc[i]; }
#pragma unroll
  for (int off = 1; off < 64; off <<= 1) {
    sum += __shfl_xor(sum, off);
    sq  += __shfl_xor(sq, off);
  }
  const float mu  = sum / HC;
  const float var = sq / HC - mu * mu;
  const float r   = rsqrtf(var + 1e-5f);
  float y[F];
#pragma unroll
  for (int i = 0; i < F; i += 4) {
    const float4 gg = *(const float4*)&lng[lane * F + i];
    const float4 bl = *(const float4*)&lnb[lane * F + i];
    y[i + 0] = (acc[i + 0] - mu) * r * gg.x + bl.x;
    y[i + 1] = (acc[i + 1] - mu) * r * gg.y + bl.y;
    y[i + 2] = (acc[i + 2] - mu) * r * gg.z + bl.z;
    y[i + 3] = (acc[i + 3] - mu) * r * gg.w + bl.w;
  }
  if constexpr (RELU) {
#pragma unroll
    for (int i = 0; i < F; ++i) y[i] = fmaxf(y[i], 0.f);
  }
  if constexpr (BFOUT) {
    unsigned short* op = &obf[(size_t)n * HC + lane * F];
    *(ushort4*)op = make_ushort4(f2b(y[0]), f2b(y[1]), f2b(y[2]), f2b(y[3]));
    if constexpr (F == 8)
      *(ushort4*)(op + 4) = make_ushort4(f2b(y[4]), f2b(y[5]), f2b(y[6]), f2b(y[7]));
  } else {
    float* op = &of32[(size_t)n * HC + lane * F];
    *(float4*)op = make_float4(y[0], y[1], y[2], y[3]);
    if constexpr (F == 8)
      *(float4*)(op + 4) = make_float4(y[4], y[5], y[6], y[7]);
  }
}

// ---------------------------------------------------------- global mean pool
__global__ __launch_bounds__(256)
void pool_partial(const unsigned short* __restrict__ x, const int* __restrict__ batch,
                  float* __restrict__ tmp, int* __restrict__ cnt, int Nn) {
  const int r0 = blockIdx.x * 64;
  const int rend = min(r0 + 64, Nn);
  const int t = threadIdx.x;
  float acc = 0.f;
  int cur = batch[r0];
  int seglen = 0;
  for (int r = r0; r < rend; ++r) {
    const int g = batch[r];
    if (g != cur) {
      unsafeAtomicAdd(&tmp[cur * 256 + t], acc);
      if (t == 0) atomicAdd(&cnt[cur], seglen);
      acc = 0.f; seglen = 0; cur = g;
    }
    acc += b2f(x[(size_t)r * 256 + t]);
    ++seglen;
  }
  unsafeAtomicAdd(&tmp[cur * 256 + t], acc);
  if (t == 0) atomicAdd(&cnt[cur], seglen);
}

__global__ __launch_bounds__(256)
void pool_final(const float* __restrict__ tmp, const int* __restrict__ cnt,
                float* __restrict__ out) {
  const int g = blockIdx.x;
  const int t = threadIdx.x;
  out[g * 256 + t] = tmp[g * 256 + t] / fmaxf((float)cnt[g], 1.f);
}

// ---------------------------------------------------------------------------
extern "C" void kernel_launch(void* const* d_in, const int* in_sizes, int n_in,
                              void* d_out, int out_size, void* d_ws, size_t ws_size,
                              hipStream_t stream) {
  const float* x    = (const float*)d_in[0];
  const int*   ei   = (const int*)d_in[1];
  const int*   batch= (const int*)d_in[2];
  const float* W1   = (const float*)d_in[3];
  const float* as1  = (const float*)d_in[4];
  const float* ad1  = (const float*)d_in[5];
  const float* b1   = (const float*)d_in[6];
  const float* g1   = (const float*)d_in[7];
  const float* be1  = (const float*)d_in[8];
  const float* W2   = (const float*)d_in[9];
  const float* as2  = (const float*)d_in[10];
  const float* ad2  = (const float*)d_in[11];
  const float* b2   = (const float*)d_in[12];
  const float* g2   = (const float*)d_in[13];
  const float* be2  = (const float*)d_in[14];

  const int N    = in_sizes[0] / 256;   // 50000
  const int E    = in_sizes[1] / 2;     // 400000
  const int Etot = E + N;
  const int Mpad = ((N + 127) / 128) * 128;   // 50048
  const int NB   = (N + 1023) / 1024;         // scan blocks (49)

  // ---------------- workspace layout ----------------
  float* ws = (float*)d_ws;
  unsigned short* out2 = (unsigned short*)ws;          // N*256 bf16
  unsigned short* A2bf = out2 + (size_t)N * 256;       // Mpad*512 bf16
  unsigned short* A1bf = A2bf;                         // Mpad*256 bf16
  unsigned short* h1bf = A2bf + (size_t)Mpad * 512;    // N*512 bf16 (h2bf aliases)
  unsigned short* W1T  = h1bf + (size_t)N * 512;       // 512*256 bf16
  unsigned short* W2T  = W1T + 512 * 256;              // 256*512 bf16
  float* es1 = (float*)(W2T + 512 * 256);              // N*4
  float* ed1 = es1 + (size_t)N * 4;                    // N*4
  float* es2 = ed1 + (size_t)N * 4;                    // 2N (per-bcol partials)
  float* ed2 = es2 + (size_t)N * 2;                    // 2N
  int* count  = (int*)(ed2 + (size_t)N * 2);           // N
  int* rowptr = count + N;                             // N+1 (+pad)
  int* cursor = rowptr + N + 4;                        // N
  int* srcs   = cursor + N;                            // Etot
  int* dsts   = srcs + Etot;                           // Etot
  float* exCSR = (float*)(dsts + Etot);                // Etot*4
  float* ptmp = exCSR + (size_t)Etot * 4;              // 64*256
  int*   pcnt = (int*)(ptmp + 64 * 256);               // 64
  int*   bsum = pcnt + 64;                             // NB
  int*   boff = bsum + 64;                             // NB
  unsigned short* h2bf = h1bf;

  const int eb = (Etot + 255) / 256;

  // ---- zero-init: es1,ed1 (8N) + es2,ed2 (4N) + count (N) contiguous ----
  hipMemsetAsync(es1, 0, (size_t)N * 13 * 4, stream);
  hipMemsetAsync(ptmp, 0, (size_t)(64 * 256 + 64) * 4, stream);
  hipMemsetAsync(A2bf + (size_t)N * 512, 0, (size_t)(Mpad - N) * 512 * 2, stream);

  // ---- prep: x->bf16 pad + degree count, weight transposes ----
  prep_x_count<<<(Mpad * 64 + 255) / 256, 256, 0, stream>>>(
      x, A1bf, N, Mpad, ei, E, Etot, count);
  cvt_wts<<<(2 * 512 * 256 + 255) / 256, 256, 0, stream>>>(W1, W2, W1T, W2T);

  // ---- CSR build ----
  scan_blocksum<<<NB, 256, 0, stream>>>(count, bsum, N);
  scan_top<<<1, 64, 0, stream>>>(bsum, boff, &rowptr[N], NB);
  scan_apply<<<NB, 256, 0, stream>>>(count, boff, rowptr, cursor, N);
  csr_scatter<<<eb, 256, 0, stream>>>(ei, E, Etot, cursor, srcs, dsts);

  // ---- layer 1: GATConv(256 -> 4x128) + LN + ReLU ----
  gemm_bf16<8><<<dim3(4, Mpad / 128), 256, 0, stream>>>(
      A1bf, W1T, h1bf, N, 512, 256, as1, ad1, es1, ed1, 4, 7, 0);
  ex_compute<4><<<eb, 256, 0, stream>>>(srcs, dsts, es1, ed1, exCSR, Etot, 0);
  gat_agg_ln<4, 128, true, true><<<(N + 3) / 4, 256, 0, stream>>>(
      rowptr, srcs, exCSR, h1bf, b1, g1, be1, A2bf, nullptr, N);

  // ---- layer 2: GATConv(512 -> 1x256) + LN ----
  gemm_bf16<16><<<dim3(2, Mpad / 128), 256, 0, stream>>>(
      A2bf, W2T, h2bf, N, 256, 512, as2, ad2, es2, ed2, 1, 8, N);
  ex_compute<1><<<eb, 256, 0, stream>>>(srcs, dsts, es2, ed2, exCSR, Etot, N);
  gat_agg_ln<1, 256, false, true><<<(N + 3) / 4, 256, 0, stream>>>(
      rowptr, srcs, exCSR, h2bf, b2, g2, be2, out2, nullptr, N);

  // ---- global mean pool ----
  pool_partial<<<(N + 63) / 64, 256, 0, stream>>>(out2, batch, ptmp, pcnt, N);
  pool_final<<<64, 256, 0, stream>>>(ptmp, pcnt, (float*)d_out);
}